// Round 7
// baseline (137.780 us; speedup 1.0000x reference)
//
#include <hip/hip_runtime.h>

// Reference collapses: softmax over axis of size 1 == 1.0, so
// out[e] = sum_f h[edge_src[e], f].  W/b/leaky_relu/edge_dst are dead.
//
// Fused persistent kernel, grid barrier with LOW-RATE polling:
//   R4=224us (acquire/poll + s_sleep(1)) vs R6=120us (relaxed + s_sleep(16))
//   -> cost is poll congestion at the one barrier cacheline (512 pollers /
//   0.43us = ~1190 tx/us >> ~200/us service rate -> saturated queues).
//   Fix: s_sleep(127) (~3.4us period -> ~150 tx/us, under capacity).
// Phase-2 index loads (4x int4/thread) are prefetched BEFORE the barrier --
// they don't depend on rowsum, so they hide under the wait.
// Counter zeroed per call by hipMemsetAsync (capture-legal, proven R3/R4/R6).

#define FDIM 128
#define NBLK 512
#define BLOCK 256

__global__ __launch_bounds__(BLOCK, 4) void fused_kernel(
    const float4* __restrict__ h4, const int* __restrict__ esrc,
    float* __restrict__ rowsum, float* __restrict__ out,
    unsigned* __restrict__ bar, int N, int E) {
    const int lane = threadIdx.x & 63;
    const int half = lane >> 5;        // which row of the pair
    const int l32  = lane & 31;
    const int wave = (blockIdx.x * BLOCK + threadIdx.x) >> 6;
    const int nw   = (NBLK * BLOCK) >> 6;
    const int Pm   = N / 2;
    const int P    = (N + 1) / 2;

    // ---- phase 1: rowsum (2 rows/wave, float4/lane, unroll x4) ----
    int i = wave;
    for (; i + 3 * nw < Pm; i += 4 * nw) {
        const int r0 = 2 * i + half;
        const int r1 = 2 * (i + nw) + half;
        const int r2 = 2 * (i + 2 * nw) + half;
        const int r3 = 2 * (i + 3 * nw) + half;
        const float4 v0 = h4[(size_t)r0 * 32 + l32];
        const float4 v1 = h4[(size_t)r1 * 32 + l32];
        const float4 v2 = h4[(size_t)r2 * 32 + l32];
        const float4 v3 = h4[(size_t)r3 * 32 + l32];
        float s0 = (v0.x + v0.y) + (v0.z + v0.w);
        float s1 = (v1.x + v1.y) + (v1.z + v1.w);
        float s2 = (v2.x + v2.y) + (v2.z + v2.w);
        float s3 = (v3.x + v3.y) + (v3.z + v3.w);
#pragma unroll
        for (int off = 16; off > 0; off >>= 1) {
            s0 += __shfl_xor(s0, off, 64);
            s1 += __shfl_xor(s1, off, 64);
            s2 += __shfl_xor(s2, off, 64);
            s3 += __shfl_xor(s3, off, 64);
        }
        if (l32 == 0) {
            rowsum[r0] = s0;
            rowsum[r1] = s1;
            rowsum[r2] = s2;
            rowsum[r3] = s3;
        }
    }
    for (; i < P; i += nw) {
        const int r = 2 * i + half;
        if (r < N) {
            const float4 v = h4[(size_t)r * 32 + l32];
            float s = (v.x + v.y) + (v.z + v.w);
#pragma unroll
            for (int off = 16; off > 0; off >>= 1) s += __shfl_xor(s, off, 64);
            if (l32 == 0) rowsum[r] = s;
        }
    }

    // ---- prefetch phase-2 indices (independent of rowsum) ----
    const int Q      = E / 4;
    const int t      = blockIdx.x * BLOCK + threadIdx.x;
    const int stride = NBLK * BLOCK;
    const int4* esrc4 = reinterpret_cast<const int4*>(esrc);
    int4 ia0 = make_int4(0, 0, 0, 0), ia1 = ia0, ia2 = ia0, ia3 = ia0;
    if (t < Q)              ia0 = esrc4[t];
    if (t + stride < Q)     ia1 = esrc4[t + stride];
    if (t + 2 * stride < Q) ia2 = esrc4[t + 2 * stride];
    if (t + 3 * stride < Q) ia3 = esrc4[t + 3 * stride];

    // ---- grid barrier (512 blocks, 4 waves; VGPR<=64 -> co-resident) ----
    __threadfence();                         // release rowsum device-wide
    __syncthreads();
    if (threadIdx.x == 0) {
        __hip_atomic_fetch_add(bar, 1u, __ATOMIC_RELAXED,
                               __HIP_MEMORY_SCOPE_AGENT);
        while (__hip_atomic_load(bar, __ATOMIC_RELAXED,
                                 __HIP_MEMORY_SCOPE_AGENT) < (unsigned)NBLK) {
            __builtin_amdgcn_s_sleep(127);   // ~8128 cy (~3.4us) per poll
        }
    }
    __syncthreads();
    __threadfence();                         // acquire: see remote rowsum

    // ---- phase 2: gather (prefetched indices, static unroll) ----
    if (t < Q) {
        float4 o;
        o.x = rowsum[ia0.x]; o.y = rowsum[ia0.y];
        o.z = rowsum[ia0.z]; o.w = rowsum[ia0.w];
        *reinterpret_cast<float4*>(out + t * 4) = o;
    }
    if (t + stride < Q) {
        float4 o;
        o.x = rowsum[ia1.x]; o.y = rowsum[ia1.y];
        o.z = rowsum[ia1.z]; o.w = rowsum[ia1.w];
        *reinterpret_cast<float4*>(out + (t + stride) * 4) = o;
    }
    if (t + 2 * stride < Q) {
        float4 o;
        o.x = rowsum[ia2.x]; o.y = rowsum[ia2.y];
        o.z = rowsum[ia2.z]; o.w = rowsum[ia2.w];
        *reinterpret_cast<float4*>(out + (t + 2 * stride) * 4) = o;
    }
    if (t + 3 * stride < Q) {
        float4 o;
        o.x = rowsum[ia3.x]; o.y = rowsum[ia3.y];
        o.z = rowsum[ia3.z]; o.w = rowsum[ia3.w];
        *reinterpret_cast<float4*>(out + (t + 3 * stride) * 4) = o;
    }
    const int rem = Q * 4 + t;               // tail (E not multiple of 4)
    if (rem < E) out[rem] = rowsum[esrc[rem]];
}

extern "C" void kernel_launch(void* const* d_in, const int* in_sizes, int n_in,
                              void* d_out, int out_size, void* d_ws, size_t ws_size,
                              hipStream_t stream) {
    const float* h    = (const float*)d_in[0];   // [N, 128]
    const int*   esrc = (const int*)d_in[3];     // [E]
    float* out    = (float*)d_out;               // [E]
    float* rowsum = (float*)d_ws;                // [N] floats
    unsigned* bar = (unsigned*)((char*)d_ws + (1 << 20));  // 1 MB offset

    const int N = in_sizes[0] / FDIM;
    const int E = in_sizes[3];

    hipMemsetAsync(bar, 0, sizeof(unsigned), stream);
    fused_kernel<<<NBLK, BLOCK, 0, stream>>>(
        reinterpret_cast<const float4*>(h), esrc, rowsum, out, bar, N, E);
}

// Round 8
// 50.024 us; speedup vs baseline: 2.7543x; 2.7543x over previous
//
#include <hip/hip_runtime.h>

// Reference collapses: softmax over axis of size 1 == 1.0, so
// out[e] = sum_f h[edge_src[e], f].  W/b/leaky_relu/edge_dst are dead.
//
// Fused persistent kernel, grid barrier with NO bulk cache maintenance:
//   R4/R6/R7 showed 120-224us regardless of poll rate -> cost was the
//   per-wave __threadfence() storm (2048x buffer_wbl2 + buffer_inv).
//   Fix: (a) rowsum written via agent-scope RELAXED atomic stores
//   (write-through to L3, no dirty L2 lines -> no wbl2 needed);
//   (b) after the spin, ONE acquire fence per block (wave 0 only,
//   512 buffer_inv total) so normal cached gather loads see fresh data;
//   (c) relaxed add + relaxed spin + s_sleep(64).
// Counter zeroed per call by hipMemsetAsync (capture-legal).

#define FDIM 128
#define NBLK 512
#define BLOCK 256

__global__ __launch_bounds__(BLOCK, 4) void fused_kernel(
    const float4* __restrict__ h4, const int* __restrict__ esrc,
    float* __restrict__ rowsum, float* __restrict__ out,
    unsigned* __restrict__ bar, int N, int E) {
    const int lane = threadIdx.x & 63;
    const int half = lane >> 5;        // which row of the pair
    const int l32  = lane & 31;
    const int wave = (blockIdx.x * BLOCK + threadIdx.x) >> 6;
    const int nw   = (NBLK * BLOCK) >> 6;
    const int Pm   = N / 2;
    const int P    = (N + 1) / 2;

    // ---- phase 1: rowsum (2 rows/wave, float4/lane, unroll x4) ----
    // rowsum stores are agent-scope write-through: visible at the
    // coherence point once vmcnt retires; no L2 writeback ever needed.
    int i = wave;
    for (; i + 3 * nw < Pm; i += 4 * nw) {
        const int r0 = 2 * i + half;
        const int r1 = 2 * (i + nw) + half;
        const int r2 = 2 * (i + 2 * nw) + half;
        const int r3 = 2 * (i + 3 * nw) + half;
        const float4 v0 = h4[(size_t)r0 * 32 + l32];
        const float4 v1 = h4[(size_t)r1 * 32 + l32];
        const float4 v2 = h4[(size_t)r2 * 32 + l32];
        const float4 v3 = h4[(size_t)r3 * 32 + l32];
        float s0 = (v0.x + v0.y) + (v0.z + v0.w);
        float s1 = (v1.x + v1.y) + (v1.z + v1.w);
        float s2 = (v2.x + v2.y) + (v2.z + v2.w);
        float s3 = (v3.x + v3.y) + (v3.z + v3.w);
#pragma unroll
        for (int off = 16; off > 0; off >>= 1) {
            s0 += __shfl_xor(s0, off, 64);
            s1 += __shfl_xor(s1, off, 64);
            s2 += __shfl_xor(s2, off, 64);
            s3 += __shfl_xor(s3, off, 64);
        }
        if (l32 == 0) {
            __hip_atomic_store(&rowsum[r0], s0, __ATOMIC_RELAXED,
                               __HIP_MEMORY_SCOPE_AGENT);
            __hip_atomic_store(&rowsum[r1], s1, __ATOMIC_RELAXED,
                               __HIP_MEMORY_SCOPE_AGENT);
            __hip_atomic_store(&rowsum[r2], s2, __ATOMIC_RELAXED,
                               __HIP_MEMORY_SCOPE_AGENT);
            __hip_atomic_store(&rowsum[r3], s3, __ATOMIC_RELAXED,
                               __HIP_MEMORY_SCOPE_AGENT);
        }
    }
    for (; i < P; i += nw) {
        const int r = 2 * i + half;
        if (r < N) {
            const float4 v = h4[(size_t)r * 32 + l32];
            float s = (v.x + v.y) + (v.z + v.w);
#pragma unroll
            for (int off = 16; off > 0; off >>= 1) s += __shfl_xor(s, off, 64);
            if (l32 == 0)
                __hip_atomic_store(&rowsum[r], s, __ATOMIC_RELAXED,
                                   __HIP_MEMORY_SCOPE_AGENT);
        }
    }

    // ---- prefetch phase-2 indices into registers (independent of rowsum;
    //      also immune to the buffer_inv below) ----
    const int Q      = E / 4;
    const int t      = blockIdx.x * BLOCK + threadIdx.x;
    const int stride = NBLK * BLOCK;
    const int4* esrc4 = reinterpret_cast<const int4*>(esrc);
    int4 ia0 = make_int4(0, 0, 0, 0), ia1 = ia0, ia2 = ia0, ia3 = ia0;
    if (t < Q)              ia0 = esrc4[t];
    if (t + stride < Q)     ia1 = esrc4[t + stride];
    if (t + 2 * stride < Q) ia2 = esrc4[t + 2 * stride];
    if (t + 3 * stride < Q) ia3 = esrc4[t + 3 * stride];

    // ---- grid barrier: no fences, relaxed only.  __syncthreads drains
    //      vmcnt -> all this block's write-through stores are at L3 before
    //      the counter bump.  512 blocks, VGPR<=64 -> co-resident. ----
    __syncthreads();
    if (threadIdx.x == 0) {
        __hip_atomic_fetch_add(bar, 1u, __ATOMIC_RELAXED,
                               __HIP_MEMORY_SCOPE_AGENT);
        while (__hip_atomic_load(bar, __ATOMIC_RELAXED,
                                 __HIP_MEMORY_SCOPE_AGENT) < (unsigned)NBLK) {
            __builtin_amdgcn_s_sleep(64);    // ~4096 cy (~1.7us) per poll
        }
    }
    __syncthreads();
    // ONE acquire fence per block (wave 0): invalidates this CU's L1 and
    // the XCD's L2 so the cached gather loads below fetch fresh rowsum
    // from the coherence point.  512 invs total, not 2048 wb+inv pairs.
    if (threadIdx.x < 64)
        __builtin_amdgcn_fence(__ATOMIC_ACQUIRE, "agent");
    __syncthreads();

    // ---- phase 2: gather (normal cached loads; rowsum refills L2) ----
    if (t < Q) {
        float4 o;
        o.x = rowsum[ia0.x]; o.y = rowsum[ia0.y];
        o.z = rowsum[ia0.z]; o.w = rowsum[ia0.w];
        *reinterpret_cast<float4*>(out + t * 4) = o;
    }
    if (t + stride < Q) {
        float4 o;
        o.x = rowsum[ia1.x]; o.y = rowsum[ia1.y];
        o.z = rowsum[ia1.z]; o.w = rowsum[ia1.w];
        *reinterpret_cast<float4*>(out + (t + stride) * 4) = o;
    }
    if (t + 2 * stride < Q) {
        float4 o;
        o.x = rowsum[ia2.x]; o.y = rowsum[ia2.y];
        o.z = rowsum[ia2.z]; o.w = rowsum[ia2.w];
        *reinterpret_cast<float4*>(out + (t + 2 * stride) * 4) = o;
    }
    if (t + 3 * stride < Q) {
        float4 o;
        o.x = rowsum[ia3.x]; o.y = rowsum[ia3.y];
        o.z = rowsum[ia3.z]; o.w = rowsum[ia3.w];
        *reinterpret_cast<float4*>(out + (t + 3 * stride) * 4) = o;
    }
    const int rem = Q * 4 + t;               // tail (E not multiple of 4)
    if (rem < E) out[rem] = rowsum[esrc[rem]];
}

extern "C" void kernel_launch(void* const* d_in, const int* in_sizes, int n_in,
                              void* d_out, int out_size, void* d_ws, size_t ws_size,
                              hipStream_t stream) {
    const float* h    = (const float*)d_in[0];   // [N, 128]
    const int*   esrc = (const int*)d_in[3];     // [E]
    float* out    = (float*)d_out;               // [E]
    float* rowsum = (float*)d_ws;                // [N] floats
    unsigned* bar = (unsigned*)((char*)d_ws + (1 << 20));  // 1 MB offset

    const int N = in_sizes[0] / FDIM;
    const int E = in_sizes[3];

    hipMemsetAsync(bar, 0, sizeof(unsigned), stream);
    fused_kernel<<<NBLK, BLOCK, 0, stream>>>(
        reinterpret_cast<const float4*>(h), esrc, rowsum, out, bar, N, E);
}

// Round 9
// 47.558 us; speedup vs baseline: 2.8971x; 1.0518x over previous
//
#include <hip/hip_runtime.h>

// Reference collapses: softmax over axis of size 1 == 1.0, so
// out[e] = sum_f h[edge_src[e], f].  W/b/leaky_relu/edge_dst are dead.
//
// Fused persistent kernel with a ZERO-cache-maintenance grid barrier:
//   R7->R8: removing 2048 per-wave wb/inv fences cut 138->50us; the
//   remaining ~35us matches 512 per-block agent-acquire fences (each a
//   full-XCD-L2 invalidate, ~64 serialized per XCD).  This version has NO
//   fences at all:
//     - rowsum written with agent-scope RELAXED atomic stores
//       (write-through to the memory-side Infinity Cache; L2 never dirty)
//     - rowsum read in phase 2 with agent-scope RELAXED atomic loads
//       (L2-bypassing; reads the coherence point directly)
//   Neither side can observe stale L2 on any replay, first included.
//   __syncthreads() before the counter bump drains vmcnt, so all
//   write-through stores are at L3 before this block is counted.
// Counter zeroed per call by hipMemsetAsync (capture-legal).

#define FDIM 128
#define NBLK 512
#define BLOCK 256

__global__ __launch_bounds__(BLOCK, 4) void fused_kernel(
    const float4* __restrict__ h4, const int* __restrict__ esrc,
    float* __restrict__ rowsum, float* __restrict__ out,
    unsigned* __restrict__ bar, int N, int E) {
    const int lane = threadIdx.x & 63;
    const int half = lane >> 5;        // which row of the pair
    const int l32  = lane & 31;
    const int wave = (blockIdx.x * BLOCK + threadIdx.x) >> 6;
    const int nw   = (NBLK * BLOCK) >> 6;
    const int Pm   = N / 2;
    const int P    = (N + 1) / 2;

    // ---- phase 1: rowsum (2 rows/wave, float4/lane, unroll x4) ----
    int i = wave;
    for (; i + 3 * nw < Pm; i += 4 * nw) {
        const int r0 = 2 * i + half;
        const int r1 = 2 * (i + nw) + half;
        const int r2 = 2 * (i + 2 * nw) + half;
        const int r3 = 2 * (i + 3 * nw) + half;
        const float4 v0 = h4[(size_t)r0 * 32 + l32];
        const float4 v1 = h4[(size_t)r1 * 32 + l32];
        const float4 v2 = h4[(size_t)r2 * 32 + l32];
        const float4 v3 = h4[(size_t)r3 * 32 + l32];
        float s0 = (v0.x + v0.y) + (v0.z + v0.w);
        float s1 = (v1.x + v1.y) + (v1.z + v1.w);
        float s2 = (v2.x + v2.y) + (v2.z + v2.w);
        float s3 = (v3.x + v3.y) + (v3.z + v3.w);
#pragma unroll
        for (int off = 16; off > 0; off >>= 1) {
            s0 += __shfl_xor(s0, off, 64);
            s1 += __shfl_xor(s1, off, 64);
            s2 += __shfl_xor(s2, off, 64);
            s3 += __shfl_xor(s3, off, 64);
        }
        if (l32 == 0) {
            __hip_atomic_store(&rowsum[r0], s0, __ATOMIC_RELAXED,
                               __HIP_MEMORY_SCOPE_AGENT);
            __hip_atomic_store(&rowsum[r1], s1, __ATOMIC_RELAXED,
                               __HIP_MEMORY_SCOPE_AGENT);
            __hip_atomic_store(&rowsum[r2], s2, __ATOMIC_RELAXED,
                               __HIP_MEMORY_SCOPE_AGENT);
            __hip_atomic_store(&rowsum[r3], s3, __ATOMIC_RELAXED,
                               __HIP_MEMORY_SCOPE_AGENT);
        }
    }
    for (; i < P; i += nw) {
        const int r = 2 * i + half;
        if (r < N) {
            const float4 v = h4[(size_t)r * 32 + l32];
            float s = (v.x + v.y) + (v.z + v.w);
#pragma unroll
            for (int off = 16; off > 0; off >>= 1) s += __shfl_xor(s, off, 64);
            if (l32 == 0)
                __hip_atomic_store(&rowsum[r], s, __ATOMIC_RELAXED,
                                   __HIP_MEMORY_SCOPE_AGENT);
        }
    }

    // ---- prefetch phase-2 indices into registers (independent of rowsum) ----
    const int Q      = E / 4;
    const int t      = blockIdx.x * BLOCK + threadIdx.x;
    const int stride = NBLK * BLOCK;
    const int4* esrc4 = reinterpret_cast<const int4*>(esrc);
    int4 ia0 = make_int4(0, 0, 0, 0), ia1 = ia0, ia2 = ia0, ia3 = ia0;
    if (t < Q)              ia0 = esrc4[t];
    if (t + stride < Q)     ia1 = esrc4[t + stride];
    if (t + 2 * stride < Q) ia2 = esrc4[t + 2 * stride];
    if (t + 3 * stride < Q) ia3 = esrc4[t + 3 * stride];

    // ---- grid barrier: relaxed only, NO fences.  __syncthreads drains
    //      vmcnt -> this block's write-through stores are at L3 before the
    //      counter bump.  512 blocks, VGPR<=64 -> all co-resident. ----
    __syncthreads();
    if (threadIdx.x == 0) {
        __hip_atomic_fetch_add(bar, 1u, __ATOMIC_RELAXED,
                               __HIP_MEMORY_SCOPE_AGENT);
        while (__hip_atomic_load(bar, __ATOMIC_RELAXED,
                                 __HIP_MEMORY_SCOPE_AGENT) < (unsigned)NBLK) {
            __builtin_amdgcn_s_sleep(32);    // ~2048 cy (~0.9us) per poll
        }
    }
    __syncthreads();

    // ---- phase 2: gather via L2-bypassing loads (coherence point reads;
    //      no fence needed, no stale-L2 hazard on any replay) ----
#define RSUM(idx) __hip_atomic_load(&rowsum[idx], __ATOMIC_RELAXED, \
                                    __HIP_MEMORY_SCOPE_AGENT)
    if (t < Q) {
        float4 o;
        o.x = RSUM(ia0.x); o.y = RSUM(ia0.y);
        o.z = RSUM(ia0.z); o.w = RSUM(ia0.w);
        *reinterpret_cast<float4*>(out + t * 4) = o;
    }
    if (t + stride < Q) {
        float4 o;
        o.x = RSUM(ia1.x); o.y = RSUM(ia1.y);
        o.z = RSUM(ia1.z); o.w = RSUM(ia1.w);
        *reinterpret_cast<float4*>(out + (t + stride) * 4) = o;
    }
    if (t + 2 * stride < Q) {
        float4 o;
        o.x = RSUM(ia2.x); o.y = RSUM(ia2.y);
        o.z = RSUM(ia2.z); o.w = RSUM(ia2.w);
        *reinterpret_cast<float4*>(out + (t + 2 * stride) * 4) = o;
    }
    if (t + 3 * stride < Q) {
        float4 o;
        o.x = RSUM(ia3.x); o.y = RSUM(ia3.y);
        o.z = RSUM(ia3.z); o.w = RSUM(ia3.w);
        *reinterpret_cast<float4*>(out + (t + 3 * stride) * 4) = o;
    }
    const int rem = Q * 4 + t;               // tail (E not multiple of 4)
    if (rem < E) out[rem] = RSUM(esrc[rem]);
#undef RSUM
}

extern "C" void kernel_launch(void* const* d_in, const int* in_sizes, int n_in,
                              void* d_out, int out_size, void* d_ws, size_t ws_size,
                              hipStream_t stream) {
    const float* h    = (const float*)d_in[0];   // [N, 128]
    const int*   esrc = (const int*)d_in[3];     // [E]
    float* out    = (float*)d_out;               // [E]
    float* rowsum = (float*)d_ws;                // [N] floats
    unsigned* bar = (unsigned*)((char*)d_ws + (1 << 20));  // 1 MB offset

    const int N = in_sizes[0] / FDIM;
    const int E = in_sizes[3];

    hipMemsetAsync(bar, 0, sizeof(unsigned), stream);
    fused_kernel<<<NBLK, BLOCK, 0, stream>>>(
        reinterpret_cast<const float4*>(h), esrc, rowsum, out, bar, N, E);
}

// Round 10
// 46.481 us; speedup vs baseline: 2.9642x; 1.0232x over previous
//
#include <hip/hip_runtime.h>

// Reference collapses: softmax over axis of size 1 == 1.0, so
// out[e] = sum_f h[edge_src[e], f].  W/b/leaky_relu/edge_dst are dead.
//
// Fused persistent kernel.  A/B vs R9: ONLY phase-2 load type changed
// (agent-scope bypass atomic loads -> plain cached loads).  Why cached is
// safe with NO fence/invalidate:
//   - every HIP dispatch begins with an agent acquire (L2 invalidate; this
//     is how kernels see host/poison writes) and ends with a release
//     writeback -> at kernel start no XCD L2 holds any rowsum line;
//   - nothing reads rowsum before the barrier in this kernel;
//   - phase-1 rowsum stores are agent-scope write-through (values at L3
//     before the counter bump -- proven by R9, where fence-free bypass
//     readers saw correct data);
//   => phase-2's first cached read of each rowsum line MUST miss to L3.
// R9's ~32us overhead is attributed to 1.6M scalar L2-bypass gather loads
// (~4 outstanding/wave, ~700cy each); cached loads hit the 400KB table in
// L2 after first touch.
// Counter zeroed per call by hipMemsetAsync (capture-legal).

#define FDIM 128
#define NBLK 512
#define BLOCK 256

__global__ __launch_bounds__(BLOCK, 4) void fused_kernel(
    const float4* __restrict__ h4, const int* __restrict__ esrc,
    float* __restrict__ rowsum, float* __restrict__ out,
    unsigned* __restrict__ bar, int N, int E) {
    const int lane = threadIdx.x & 63;
    const int half = lane >> 5;        // which row of the pair
    const int l32  = lane & 31;
    const int wave = (blockIdx.x * BLOCK + threadIdx.x) >> 6;
    const int nw   = (NBLK * BLOCK) >> 6;
    const int Pm   = N / 2;
    const int P    = (N + 1) / 2;

    // ---- phase 1: rowsum (2 rows/wave, float4/lane, unroll x4) ----
    int i = wave;
    for (; i + 3 * nw < Pm; i += 4 * nw) {
        const int r0 = 2 * i + half;
        const int r1 = 2 * (i + nw) + half;
        const int r2 = 2 * (i + 2 * nw) + half;
        const int r3 = 2 * (i + 3 * nw) + half;
        const float4 v0 = h4[(size_t)r0 * 32 + l32];
        const float4 v1 = h4[(size_t)r1 * 32 + l32];
        const float4 v2 = h4[(size_t)r2 * 32 + l32];
        const float4 v3 = h4[(size_t)r3 * 32 + l32];
        float s0 = (v0.x + v0.y) + (v0.z + v0.w);
        float s1 = (v1.x + v1.y) + (v1.z + v1.w);
        float s2 = (v2.x + v2.y) + (v2.z + v2.w);
        float s3 = (v3.x + v3.y) + (v3.z + v3.w);
#pragma unroll
        for (int off = 16; off > 0; off >>= 1) {
            s0 += __shfl_xor(s0, off, 64);
            s1 += __shfl_xor(s1, off, 64);
            s2 += __shfl_xor(s2, off, 64);
            s3 += __shfl_xor(s3, off, 64);
        }
        if (l32 == 0) {
            __hip_atomic_store(&rowsum[r0], s0, __ATOMIC_RELAXED,
                               __HIP_MEMORY_SCOPE_AGENT);
            __hip_atomic_store(&rowsum[r1], s1, __ATOMIC_RELAXED,
                               __HIP_MEMORY_SCOPE_AGENT);
            __hip_atomic_store(&rowsum[r2], s2, __ATOMIC_RELAXED,
                               __HIP_MEMORY_SCOPE_AGENT);
            __hip_atomic_store(&rowsum[r3], s3, __ATOMIC_RELAXED,
                               __HIP_MEMORY_SCOPE_AGENT);
        }
    }
    for (; i < P; i += nw) {
        const int r = 2 * i + half;
        if (r < N) {
            const float4 v = h4[(size_t)r * 32 + l32];
            float s = (v.x + v.y) + (v.z + v.w);
#pragma unroll
            for (int off = 16; off > 0; off >>= 1) s += __shfl_xor(s, off, 64);
            if (l32 == 0)
                __hip_atomic_store(&rowsum[r], s, __ATOMIC_RELAXED,
                                   __HIP_MEMORY_SCOPE_AGENT);
        }
    }

    // ---- prefetch phase-2 indices into registers (independent of rowsum) ----
    const int Q      = E / 4;
    const int t      = blockIdx.x * BLOCK + threadIdx.x;
    const int stride = NBLK * BLOCK;
    const int4* esrc4 = reinterpret_cast<const int4*>(esrc);
    int4 ia0 = make_int4(0, 0, 0, 0), ia1 = ia0, ia2 = ia0, ia3 = ia0;
    if (t < Q)              ia0 = esrc4[t];
    if (t + stride < Q)     ia1 = esrc4[t + stride];
    if (t + 2 * stride < Q) ia2 = esrc4[t + 2 * stride];
    if (t + 3 * stride < Q) ia3 = esrc4[t + 3 * stride];

    // ---- grid barrier: relaxed only, NO fences.  __syncthreads drains
    //      vmcnt -> this block's write-through stores are at L3 before the
    //      counter bump.  512 blocks, VGPR<=64 -> all co-resident. ----
    __syncthreads();
    if (threadIdx.x == 0) {
        __hip_atomic_fetch_add(bar, 1u, __ATOMIC_RELAXED,
                               __HIP_MEMORY_SCOPE_AGENT);
        while (__hip_atomic_load(bar, __ATOMIC_RELAXED,
                                 __HIP_MEMORY_SCOPE_AGENT) < (unsigned)NBLK) {
            __builtin_amdgcn_s_sleep(32);    // ~2048 cy (~0.85us) per poll
        }
    }
    __syncthreads();

    // ---- phase 2: gather via PLAIN CACHED loads (first touch misses to
    //      L3 by the dispatch-boundary-invalidate argument above; 400KB
    //      table then L2-resident) ----
    if (t < Q) {
        float4 o;
        o.x = rowsum[ia0.x]; o.y = rowsum[ia0.y];
        o.z = rowsum[ia0.z]; o.w = rowsum[ia0.w];
        *reinterpret_cast<float4*>(out + t * 4) = o;
    }
    if (t + stride < Q) {
        float4 o;
        o.x = rowsum[ia1.x]; o.y = rowsum[ia1.y];
        o.z = rowsum[ia1.z]; o.w = rowsum[ia1.w];
        *reinterpret_cast<float4*>(out + (t + stride) * 4) = o;
    }
    if (t + 2 * stride < Q) {
        float4 o;
        o.x = rowsum[ia2.x]; o.y = rowsum[ia2.y];
        o.z = rowsum[ia2.z]; o.w = rowsum[ia2.w];
        *reinterpret_cast<float4*>(out + (t + 2 * stride) * 4) = o;
    }
    if (t + 3 * stride < Q) {
        float4 o;
        o.x = rowsum[ia3.x]; o.y = rowsum[ia3.y];
        o.z = rowsum[ia3.z]; o.w = rowsum[ia3.w];
        *reinterpret_cast<float4*>(out + (t + 3 * stride) * 4) = o;
    }
    const int rem = Q * 4 + t;               // tail (E not multiple of 4)
    if (rem < E) out[rem] = rowsum[esrc[rem]];
}

extern "C" void kernel_launch(void* const* d_in, const int* in_sizes, int n_in,
                              void* d_out, int out_size, void* d_ws, size_t ws_size,
                              hipStream_t stream) {
    const float* h    = (const float*)d_in[0];   // [N, 128]
    const int*   esrc = (const int*)d_in[3];     // [E]
    float* out    = (float*)d_out;               // [E]
    float* rowsum = (float*)d_ws;                // [N] floats
    unsigned* bar = (unsigned*)((char*)d_ws + (1 << 20));  // 1 MB offset

    const int N = in_sizes[0] / FDIM;
    const int E = in_sizes[3];

    hipMemsetAsync(bar, 0, sizeof(unsigned), stream);
    fused_kernel<<<NBLK, BLOCK, 0, stream>>>(
        reinterpret_cast<const float4*>(h), esrc, rowsum, out, bar, N, E);
}

// Round 11
// 29.129 us; speedup vs baseline: 4.7301x; 1.5957x over previous
//
#include <hip/hip_runtime.h>

// Reference collapses: softmax over axis of size 1 == 1.0, so
// out[e] = sum_f h[edge_src[e], f].  W/b/leaky_relu/edge_dst are dead.
//
// Fused persistent kernel.  A/B vs R10: ONLY the grid barrier changed.
// R8-R10 isolated a fixed ~35us cost insensitive to fences, load types,
// and L3 temperature -> attributed to single-cacheline congestion: 512
// pollers at ~600 tx/us saturate the barrier line's service pipeline and
// the arrival RMWs queue behind them.
// Fix: two-level barrier over 17 lines spaced 4KB apart (different L3
// channels): 8 group arrival counters (64 arrivals each, group=blk&7),
// 1 root counter (8 arrivals), 8 release flags (64 pollers each ->
// ~75 tx/us/line).  Ordering: __syncthreads drains vmcnt (write-through
// stores visible at L3) before the arrival add; each subsequent step is
// ordered by the observed counter value (proven fence-free safe in R9).
// Phase-2 uses plain cached loads (dispatch-boundary L2-invalidate
// argument, validated R10).  Barrier region zeroed per call by
// hipMemsetAsync (capture-legal).

#define FDIM 128
#define NBLK 512
#define BLOCK 256
#define BARLINE 4096
#define NGRP 8
#define GRPSZ (NBLK / NGRP)   // 64 blocks per group

__global__ __launch_bounds__(BLOCK, 4) void fused_kernel(
    const float4* __restrict__ h4, const int* __restrict__ esrc,
    float* __restrict__ rowsum, float* __restrict__ out,
    char* __restrict__ barbase, int N, int E) {
    const int lane = threadIdx.x & 63;
    const int half = lane >> 5;        // which row of the pair
    const int l32  = lane & 31;
    const int wave = (blockIdx.x * BLOCK + threadIdx.x) >> 6;
    const int nw   = (NBLK * BLOCK) >> 6;
    const int Pm   = N / 2;
    const int P    = (N + 1) / 2;

    // ---- phase 1: rowsum (2 rows/wave, float4/lane, unroll x4) ----
    int i = wave;
    for (; i + 3 * nw < Pm; i += 4 * nw) {
        const int r0 = 2 * i + half;
        const int r1 = 2 * (i + nw) + half;
        const int r2 = 2 * (i + 2 * nw) + half;
        const int r3 = 2 * (i + 3 * nw) + half;
        const float4 v0 = h4[(size_t)r0 * 32 + l32];
        const float4 v1 = h4[(size_t)r1 * 32 + l32];
        const float4 v2 = h4[(size_t)r2 * 32 + l32];
        const float4 v3 = h4[(size_t)r3 * 32 + l32];
        float s0 = (v0.x + v0.y) + (v0.z + v0.w);
        float s1 = (v1.x + v1.y) + (v1.z + v1.w);
        float s2 = (v2.x + v2.y) + (v2.z + v2.w);
        float s3 = (v3.x + v3.y) + (v3.z + v3.w);
#pragma unroll
        for (int off = 16; off > 0; off >>= 1) {
            s0 += __shfl_xor(s0, off, 64);
            s1 += __shfl_xor(s1, off, 64);
            s2 += __shfl_xor(s2, off, 64);
            s3 += __shfl_xor(s3, off, 64);
        }
        if (l32 == 0) {
            __hip_atomic_store(&rowsum[r0], s0, __ATOMIC_RELAXED,
                               __HIP_MEMORY_SCOPE_AGENT);
            __hip_atomic_store(&rowsum[r1], s1, __ATOMIC_RELAXED,
                               __HIP_MEMORY_SCOPE_AGENT);
            __hip_atomic_store(&rowsum[r2], s2, __ATOMIC_RELAXED,
                               __HIP_MEMORY_SCOPE_AGENT);
            __hip_atomic_store(&rowsum[r3], s3, __ATOMIC_RELAXED,
                               __HIP_MEMORY_SCOPE_AGENT);
        }
    }
    for (; i < P; i += nw) {
        const int r = 2 * i + half;
        if (r < N) {
            const float4 v = h4[(size_t)r * 32 + l32];
            float s = (v.x + v.y) + (v.z + v.w);
#pragma unroll
            for (int off = 16; off > 0; off >>= 1) s += __shfl_xor(s, off, 64);
            if (l32 == 0)
                __hip_atomic_store(&rowsum[r], s, __ATOMIC_RELAXED,
                                   __HIP_MEMORY_SCOPE_AGENT);
        }
    }

    // ---- prefetch phase-2 indices into registers (independent of rowsum) ----
    const int Q      = E / 4;
    const int t      = blockIdx.x * BLOCK + threadIdx.x;
    const int stride = NBLK * BLOCK;
    const int4* esrc4 = reinterpret_cast<const int4*>(esrc);
    int4 ia0 = make_int4(0, 0, 0, 0), ia1 = ia0, ia2 = ia0, ia3 = ia0;
    if (t < Q)              ia0 = esrc4[t];
    if (t + stride < Q)     ia1 = esrc4[t + stride];
    if (t + 2 * stride < Q) ia2 = esrc4[t + 2 * stride];
    if (t + 3 * stride < Q) ia3 = esrc4[t + 3 * stride];

    // ---- two-level grid barrier (relaxed only, no fences) ----
    //   arrival[g] : barbase + g*4096          (g = blockIdx & 7; 64 each)
    //   root       : barbase + 8*4096          (8 arrivals)
    //   release[g] : barbase + (9+g)*4096      (64 pollers each)
    __syncthreads();                       // drains vmcnt: stores at L3
    if (threadIdx.x == 0) {
        const int g = blockIdx.x & (NGRP - 1);
        unsigned* arr  = (unsigned*)(barbase + g * BARLINE);
        unsigned* root = (unsigned*)(barbase + NGRP * BARLINE);
        unsigned* rel  = (unsigned*)(barbase + (NGRP + 1 + g) * BARLINE);
        const unsigned prev = __hip_atomic_fetch_add(
            arr, 1u, __ATOMIC_RELAXED, __HIP_MEMORY_SCOPE_AGENT);
        if (prev == (unsigned)(GRPSZ - 1)) {       // group complete
            const unsigned rprev = __hip_atomic_fetch_add(
                root, 1u, __ATOMIC_RELAXED, __HIP_MEMORY_SCOPE_AGENT);
            if (rprev == (unsigned)(NGRP - 1)) {   // all groups complete
#pragma unroll
                for (int k = 0; k < NGRP; ++k)
                    __hip_atomic_store(
                        (unsigned*)(barbase + (NGRP + 1 + k) * BARLINE), 1u,
                        __ATOMIC_RELAXED, __HIP_MEMORY_SCOPE_AGENT);
            }
        }
        while (__hip_atomic_load(rel, __ATOMIC_RELAXED,
                                 __HIP_MEMORY_SCOPE_AGENT) == 0u) {
            __builtin_amdgcn_s_sleep(32);  // ~2048 cy (~0.85us) per poll
        }
    }
    __syncthreads();

    // ---- phase 2: gather via plain cached loads (validated R10) ----
    if (t < Q) {
        float4 o;
        o.x = rowsum[ia0.x]; o.y = rowsum[ia0.y];
        o.z = rowsum[ia0.z]; o.w = rowsum[ia0.w];
        *reinterpret_cast<float4*>(out + t * 4) = o;
    }
    if (t + stride < Q) {
        float4 o;
        o.x = rowsum[ia1.x]; o.y = rowsum[ia1.y];
        o.z = rowsum[ia1.z]; o.w = rowsum[ia1.w];
        *reinterpret_cast<float4*>(out + (t + stride) * 4) = o;
    }
    if (t + 2 * stride < Q) {
        float4 o;
        o.x = rowsum[ia2.x]; o.y = rowsum[ia2.y];
        o.z = rowsum[ia2.z]; o.w = rowsum[ia2.w];
        *reinterpret_cast<float4*>(out + (t + 2 * stride) * 4) = o;
    }
    if (t + 3 * stride < Q) {
        float4 o;
        o.x = rowsum[ia3.x]; o.y = rowsum[ia3.y];
        o.z = rowsum[ia3.z]; o.w = rowsum[ia3.w];
        *reinterpret_cast<float4*>(out + (t + 3 * stride) * 4) = o;
    }
    const int rem = Q * 4 + t;             // tail (E not multiple of 4)
    if (rem < E) out[rem] = rowsum[esrc[rem]];
}

extern "C" void kernel_launch(void* const* d_in, const int* in_sizes, int n_in,
                              void* d_out, int out_size, void* d_ws, size_t ws_size,
                              hipStream_t stream) {
    const float* h    = (const float*)d_in[0];   // [N, 128]
    const int*   esrc = (const int*)d_in[3];     // [E]
    float* out    = (float*)d_out;               // [E]
    float* rowsum = (float*)d_ws;                // [N] floats
    char*  barbase = (char*)d_ws + (1 << 20);    // 17 x 4KB barrier lines

    const int N = in_sizes[0] / FDIM;
    const int E = in_sizes[3];

    hipMemsetAsync(barbase, 0, (2 * NGRP + 1) * BARLINE, stream);
    fused_kernel<<<NBLK, BLOCK, 0, stream>>>(
        reinterpret_cast<const float4*>(h), esrc, rowsum, out, barbase, N, E);
}

// Round 12
// 28.786 us; speedup vs baseline: 4.7863x; 1.0119x over previous
//
#include <hip/hip_runtime.h>

// Reference collapses: softmax over axis of size 1 == 1.0, so
// out[e] = sum_f h[edge_src[e], f].  W/b/leaky_relu/edge_dst are dead.
//
// Fused persistent kernel + two-level grid barrier (R11, fixed congestion:
// 8 arrival lines x64 + root + 8 release lines x64 pollers, 4KB spacing).
// A/B vs R11: ONLY the barrier reset changed -- hipMemsetAsync(68KB) went
// through rocclr fillBufferAligned at 2.2GB/s (~10-40us); replaced with a
// one-wave zero kernel writing the 17 counters directly (agent-scope
// write-through stores -> zeros at the coherence point; stream order makes
// them visible to the fused kernel's arrival RMWs).

#define FDIM 128
#define NBLK 512
#define BLOCK 256
#define BARLINE 4096
#define NGRP 8
#define GRPSZ (NBLK / NGRP)   // 64 blocks per group

__global__ void zero_bar_kernel(char* __restrict__ barbase) {
    if (threadIdx.x < 2 * NGRP + 1)
        __hip_atomic_store((unsigned*)(barbase + threadIdx.x * BARLINE), 0u,
                           __ATOMIC_RELAXED, __HIP_MEMORY_SCOPE_AGENT);
}

__global__ __launch_bounds__(BLOCK, 4) void fused_kernel(
    const float4* __restrict__ h4, const int* __restrict__ esrc,
    float* __restrict__ rowsum, float* __restrict__ out,
    char* __restrict__ barbase, int N, int E) {
    const int lane = threadIdx.x & 63;
    const int half = lane >> 5;        // which row of the pair
    const int l32  = lane & 31;
    const int wave = (blockIdx.x * BLOCK + threadIdx.x) >> 6;
    const int nw   = (NBLK * BLOCK) >> 6;
    const int Pm   = N / 2;
    const int P    = (N + 1) / 2;

    // ---- phase 1: rowsum (2 rows/wave, float4/lane, unroll x4) ----
    int i = wave;
    for (; i + 3 * nw < Pm; i += 4 * nw) {
        const int r0 = 2 * i + half;
        const int r1 = 2 * (i + nw) + half;
        const int r2 = 2 * (i + 2 * nw) + half;
        const int r3 = 2 * (i + 3 * nw) + half;
        const float4 v0 = h4[(size_t)r0 * 32 + l32];
        const float4 v1 = h4[(size_t)r1 * 32 + l32];
        const float4 v2 = h4[(size_t)r2 * 32 + l32];
        const float4 v3 = h4[(size_t)r3 * 32 + l32];
        float s0 = (v0.x + v0.y) + (v0.z + v0.w);
        float s1 = (v1.x + v1.y) + (v1.z + v1.w);
        float s2 = (v2.x + v2.y) + (v2.z + v2.w);
        float s3 = (v3.x + v3.y) + (v3.z + v3.w);
#pragma unroll
        for (int off = 16; off > 0; off >>= 1) {
            s0 += __shfl_xor(s0, off, 64);
            s1 += __shfl_xor(s1, off, 64);
            s2 += __shfl_xor(s2, off, 64);
            s3 += __shfl_xor(s3, off, 64);
        }
        if (l32 == 0) {
            __hip_atomic_store(&rowsum[r0], s0, __ATOMIC_RELAXED,
                               __HIP_MEMORY_SCOPE_AGENT);
            __hip_atomic_store(&rowsum[r1], s1, __ATOMIC_RELAXED,
                               __HIP_MEMORY_SCOPE_AGENT);
            __hip_atomic_store(&rowsum[r2], s2, __ATOMIC_RELAXED,
                               __HIP_MEMORY_SCOPE_AGENT);
            __hip_atomic_store(&rowsum[r3], s3, __ATOMIC_RELAXED,
                               __HIP_MEMORY_SCOPE_AGENT);
        }
    }
    for (; i < P; i += nw) {
        const int r = 2 * i + half;
        if (r < N) {
            const float4 v = h4[(size_t)r * 32 + l32];
            float s = (v.x + v.y) + (v.z + v.w);
#pragma unroll
            for (int off = 16; off > 0; off >>= 1) s += __shfl_xor(s, off, 64);
            if (l32 == 0)
                __hip_atomic_store(&rowsum[r], s, __ATOMIC_RELAXED,
                                   __HIP_MEMORY_SCOPE_AGENT);
        }
    }

    // ---- prefetch phase-2 indices into registers (independent of rowsum) ----
    const int Q      = E / 4;
    const int t      = blockIdx.x * BLOCK + threadIdx.x;
    const int stride = NBLK * BLOCK;
    const int4* esrc4 = reinterpret_cast<const int4*>(esrc);
    int4 ia0 = make_int4(0, 0, 0, 0), ia1 = ia0, ia2 = ia0, ia3 = ia0;
    if (t < Q)              ia0 = esrc4[t];
    if (t + stride < Q)     ia1 = esrc4[t + stride];
    if (t + 2 * stride < Q) ia2 = esrc4[t + 2 * stride];
    if (t + 3 * stride < Q) ia3 = esrc4[t + 3 * stride];

    // ---- two-level grid barrier (relaxed only, no fences) ----
    //   arrival[g] : barbase + g*4096          (g = blockIdx & 7; 64 each)
    //   root       : barbase + 8*4096          (8 arrivals)
    //   release[g] : barbase + (9+g)*4096      (64 pollers each)
    __syncthreads();                       // drains vmcnt: stores at L3
    if (threadIdx.x == 0) {
        const int g = blockIdx.x & (NGRP - 1);
        unsigned* arr  = (unsigned*)(barbase + g * BARLINE);
        unsigned* root = (unsigned*)(barbase + NGRP * BARLINE);
        unsigned* rel  = (unsigned*)(barbase + (NGRP + 1 + g) * BARLINE);
        const unsigned prev = __hip_atomic_fetch_add(
            arr, 1u, __ATOMIC_RELAXED, __HIP_MEMORY_SCOPE_AGENT);
        if (prev == (unsigned)(GRPSZ - 1)) {       // group complete
            const unsigned rprev = __hip_atomic_fetch_add(
                root, 1u, __ATOMIC_RELAXED, __HIP_MEMORY_SCOPE_AGENT);
            if (rprev == (unsigned)(NGRP - 1)) {   // all groups complete
#pragma unroll
                for (int k = 0; k < NGRP; ++k)
                    __hip_atomic_store(
                        (unsigned*)(barbase + (NGRP + 1 + k) * BARLINE), 1u,
                        __ATOMIC_RELAXED, __HIP_MEMORY_SCOPE_AGENT);
            }
        }
        while (__hip_atomic_load(rel, __ATOMIC_RELAXED,
                                 __HIP_MEMORY_SCOPE_AGENT) == 0u) {
            __builtin_amdgcn_s_sleep(32);  // ~2048 cy (~0.85us) per poll
        }
    }
    __syncthreads();

    // ---- phase 2: gather via plain cached loads (validated R10) ----
    if (t < Q) {
        float4 o;
        o.x = rowsum[ia0.x]; o.y = rowsum[ia0.y];
        o.z = rowsum[ia0.z]; o.w = rowsum[ia0.w];
        *reinterpret_cast<float4*>(out + t * 4) = o;
    }
    if (t + stride < Q) {
        float4 o;
        o.x = rowsum[ia1.x]; o.y = rowsum[ia1.y];
        o.z = rowsum[ia1.z]; o.w = rowsum[ia1.w];
        *reinterpret_cast<float4*>(out + (t + stride) * 4) = o;
    }
    if (t + 2 * stride < Q) {
        float4 o;
        o.x = rowsum[ia2.x]; o.y = rowsum[ia2.y];
        o.z = rowsum[ia2.z]; o.w = rowsum[ia2.w];
        *reinterpret_cast<float4*>(out + (t + 2 * stride) * 4) = o;
    }
    if (t + 3 * stride < Q) {
        float4 o;
        o.x = rowsum[ia3.x]; o.y = rowsum[ia3.y];
        o.z = rowsum[ia3.z]; o.w = rowsum[ia3.w];
        *reinterpret_cast<float4*>(out + (t + 3 * stride) * 4) = o;
    }
    const int rem = Q * 4 + t;             // tail (E not multiple of 4)
    if (rem < E) out[rem] = rowsum[esrc[rem]];
}

extern "C" void kernel_launch(void* const* d_in, const int* in_sizes, int n_in,
                              void* d_out, int out_size, void* d_ws, size_t ws_size,
                              hipStream_t stream) {
    const float* h    = (const float*)d_in[0];   // [N, 128]
    const int*   esrc = (const int*)d_in[3];     // [E]
    float* out    = (float*)d_out;               // [E]
    float* rowsum = (float*)d_ws;                // [N] floats
    char*  barbase = (char*)d_ws + (1 << 20);    // 17 x 4KB barrier lines

    const int N = in_sizes[0] / FDIM;
    const int E = in_sizes[3];

    zero_bar_kernel<<<1, 64, 0, stream>>>(barbase);
    fused_kernel<<<NBLK, BLOCK, 0, stream>>>(
        reinterpret_cast<const float4*>(h), esrc, rowsum, out, barbase, N, E);
}